// Round 2
// baseline (144.582 us; speedup 1.0000x reference)
//
#include <hip/hip_runtime.h>
#include <hip/hip_cooperative_groups.h>
#include <float.h>
#include <math.h>

namespace cg = cooperative_groups;

#define B 128
#define D 128
#define N 3072      // 3*32*32
#define NP1 2048    // half-row sort size (pow2)
#define TROW 64     // row-tiles (2 rows each)
#define NTILE (TROW*(TROW+1)/2)   // 2080 upper-tri 2x2 tiles
#define GRID 256
#define NTHREADS 512

__device__ __forceinline__ void cas(float& a, float& b, bool up) {
    float lo = fminf(a, b), hi = fmaxf(a, b);
    a = up ? lo : hi;
    b = up ? hi : lo;
}

// ---------------------------------------------------------------------------
// Fused cooperative kernel: 256 blocks x 512 threads, exactly 1 block/CU.
// Phase 0: block b sorts half (row=b>>1, half=b&1); half0 DESC, half1 ASC
//          -> concatenation is a valley bitonic sequence (validated R1).
// Phase 1: zcos distributed: block b computes row (b>>1), cols (b&1)*64..+63.
// Phase 2: split bitonic merge: block (row,side) applies the j=2048
//          half-cleaner on load, then an independent 2048 ascending merge.
// Phase 3: pair tiles (validated math), waves grid-stride 2080 tiles.
// ---------------------------------------------------------------------------
__global__ __launch_bounds__(NTHREADS) void fused_kernel(const float* __restrict__ x,
                                                         const float* __restrict__ z,
                                                         float* __restrict__ xs,
                                                         float* __restrict__ zcos,
                                                         float* __restrict__ out) {
    __shared__ float smem[NP1];
    __shared__ float mx[2];
    __shared__ float partial[8];
    cg::grid_group grid = cg::this_grid();

    int tid = threadIdx.x;
    int bid = blockIdx.x;
    int row  = bid >> 1;      // x-row / z-row
    int half = bid & 1;

    // ---------------- phase 0: sort one 2048-half (validated R1 code) -----
    {
        bool flip = (half == 0);          // half0 descending, half1 ascending
        int lbase = tid * 4;              // local index in [0, 2048)
        int gbase = half * NP1 + lbase;   // global index in row's 4096 space
        float v[4];

        if (gbase < N) {
            float4 t4 = *(const float4*)(x + (size_t)row * N + gbase);
            v[0] = t4.x; v[1] = t4.y; v[2] = t4.z; v[3] = t4.w;
        } else {
            v[0] = v[1] = v[2] = v[3] = FLT_MAX;
        }

        for (int k = 2; k <= NP1; k <<= 1) {
            int j = k >> 1;
            bool ub = (((lbase & k) == 0) != flip);

            if (j >= 256) {
                ((float4*)smem)[tid] = make_float4(v[0], v[1], v[2], v[3]);
                __syncthreads();
                for (; j >= 256; j >>= 1) {
                    #pragma unroll
                    for (int u = 0; u < 2; u++) {
                        int p = tid + u * 512;          // 1024 pairs per pass
                        int i = ((p & ~(j - 1)) << 1) | (p & (j - 1));
                        int pj = i | j;
                        float a = smem[i], b2 = smem[pj];
                        bool up = (((i & k) == 0) != flip);
                        if ((a > b2) == up) { smem[i] = b2; smem[pj] = a; }
                    }
                    __syncthreads();
                }
                float4 t4 = ((float4*)smem)[tid];
                v[0] = t4.x; v[1] = t4.y; v[2] = t4.z; v[3] = t4.w;
                __syncthreads();
            }

            for (; j >= 4; j >>= 1) {
                int lx = j >> 2;
                bool keep_lower = ((tid & lx) == 0);
                bool sel = (keep_lower == ub);
                #pragma unroll
                for (int r = 0; r < 4; r++) {
                    float p = __shfl_xor(v[r], lx, 64);
                    v[r] = sel ? fminf(v[r], p) : fmaxf(v[r], p);
                }
            }
            if (j == 2) {
                cas(v[0], v[2], ub);
                cas(v[1], v[3], ub);
                j >>= 1;
            }
            {
                bool upA = ((((lbase + 0) & k) == 0) != flip);
                bool upB = ((((lbase + 2) & k) == 0) != flip);
                cas(v[0], v[1], upA);
                cas(v[2], v[3], upB);
            }
        }

        if (gbase < N)
            *(float4*)(xs + (size_t)row * N + gbase) = make_float4(v[0], v[1], v[2], v[3]);
    }
    __syncthreads();

    // ---------------- phase 1: zcos (64 entries) + out zero ---------------
    {
        // all-row inverse norms into smem[0..127] (4 threads per row)
        int r2 = tid >> 2;
        int seg = tid & 3;
        const float4* zr = (const float4*)(z + r2 * D + seg * 32);
        float s = 0.f;
        #pragma unroll
        for (int u = 0; u < 8; u++) {
            float4 vv = zr[u];
            s += vv.x * vv.x + vv.y * vv.y + vv.z * vv.z + vv.w * vv.w;
        }
        s += __shfl_down(s, 2, 4);
        s += __shfl_down(s, 1, 4);
        if (seg == 0) smem[r2] = 1.0f / fmaxf(sqrtf(s), 1e-12f);
        __syncthreads();

        // 64 entries: (row, half*64 + e), 8 threads per entry
        int e  = tid >> 3;
        int sg = tid & 7;
        int j  = half * 64 + e;
        const float4* zi = (const float4*)(z + row * D + sg * 16);
        const float4* zj = (const float4*)(z + j * D + sg * 16);
        float dot = 0.f;
        #pragma unroll
        for (int u = 0; u < 4; u++) {
            float4 a = zi[u], b = zj[u];
            dot += a.x * b.x + a.y * b.y + a.z * b.z + a.w * b.w;
        }
        dot += __shfl_down(dot, 4, 8);
        dot += __shfl_down(dot, 2, 8);
        dot += __shfl_down(dot, 1, 8);
        if (sg == 0) zcos[row * B + j] = dot * smem[row] * smem[j];

        if (bid == 0 && tid == 0) out[0] = 0.f;
    }

    grid.sync();

    // ---------------- phase 2: split bitonic merge (ascending) ------------
    {
        int lbase = tid * 4;
        const float4* xr = (const float4*)(xs + (size_t)row * N);
        float v[4];

        if (half == 0) {
            // L half: min(s_i, s_{i+2048}); partner is FLT_MAX for i>=1024
            float4 a = xr[tid];
            if (lbase < 1024) {
                float4 c = xr[tid + 512];
                v[0] = fminf(a.x, c.x); v[1] = fminf(a.y, c.y);
                v[2] = fminf(a.z, c.z); v[3] = fminf(a.w, c.w);
            } else {
                v[0] = a.x; v[1] = a.y; v[2] = a.z; v[3] = a.w;
            }
        } else {
            // H half: max(s_i, s_{i+2048}) for i<1024, FLT_MAX above
            if (lbase < 1024) {
                float4 a = xr[tid];
                float4 c = xr[tid + 512];
                v[0] = fmaxf(a.x, c.x); v[1] = fmaxf(a.y, c.y);
                v[2] = fmaxf(a.z, c.z); v[3] = fmaxf(a.w, c.w);
            } else {
                v[0] = v[1] = v[2] = v[3] = FLT_MAX;
            }
        }

        ((float4*)smem)[tid] = make_float4(v[0], v[1], v[2], v[3]);
        __syncthreads();
        for (int j = 1024; j >= 256; j >>= 1) {
            #pragma unroll
            for (int u = 0; u < 2; u++) {
                int p = tid + u * 512;
                int i = ((p & ~(j - 1)) << 1) | (p & (j - 1));
                int pj = i | j;
                float a = smem[i], b2 = smem[pj];
                if (a > b2) { smem[i] = b2; smem[pj] = a; }   // ascending
            }
            __syncthreads();
        }
        {
            float4 t4 = ((float4*)smem)[tid];
            v[0] = t4.x; v[1] = t4.y; v[2] = t4.z; v[3] = t4.w;
        }
        for (int j = 128; j >= 4; j >>= 1) {
            int lx = j >> 2;
            bool sel = ((tid & lx) == 0);
            #pragma unroll
            for (int r = 0; r < 4; r++) {
                float p = __shfl_xor(v[r], lx, 64);
                v[r] = sel ? fminf(v[r], p) : fmaxf(v[r], p);
            }
        }
        cas(v[0], v[2], true);
        cas(v[1], v[3], true);
        cas(v[0], v[1], true);
        cas(v[2], v[3], true);

        int gbase = half * NP1 + lbase;
        if (gbase < N)
            *(float4*)(xs + (size_t)row * N + gbase) = make_float4(v[0], v[1], v[2], v[3]);
    }

    grid.sync();

    // ---------------- phase 3: pair tiles (validated math) ----------------
    {
        if (tid < B) {
            float vv = zcos[tid * (B + 1)];
            #pragma unroll
            for (int o = 32; o > 0; o >>= 1) vv = fmaxf(vv, __shfl_down(vv, o, 64));
            if ((tid & 63) == 0) mx[tid >> 6] = vv;
        }
        __syncthreads();
        float maxv = fmaxf(mx[0], mx[1]);

        int w = tid >> 6;                  // wave 0..7
        int lane = tid & 63;
        float acc = 0.f;

        for (int T = bid * 8 + w; T < NTILE; T += GRID * 8) {
            // decode T -> (ti, tj), ti<=tj over TROW=64 (validated decode)
            float ff = (float)(2 * TROW + 1);
            int ti = (int)((ff - sqrtf(ff * ff - 8.0f * (float)T)) * 0.5f);
            if (ti < 0) ti = 0;
            if (ti > TROW - 1) ti = TROW - 1;
            while ((ti + 1) * TROW - ((ti + 1) * ti) / 2 <= T) ti++;
            while (ti * TROW - (ti * (ti - 1)) / 2 > T) ti--;
            int tj = ti + (T - (ti * TROW - (ti * (ti - 1)) / 2));

            int r0 = 2 * ti, r1 = r0 + 1;
            int c0 = 2 * tj, c1 = c0 + 1;

            const float4* a0 = (const float4*)(xs + (size_t)r0 * N);
            const float4* a1 = (const float4*)(xs + (size_t)r1 * N);
            const float4* b0 = (const float4*)(xs + (size_t)c0 * N);
            const float4* b1 = (const float4*)(xs + (size_t)c1 * N);

            float s00 = 0.f, s01 = 0.f, s10 = 0.f, s11 = 0.f;
            #pragma unroll
            for (int u = 0; u < N / 4 / 64; u++) {          // 12 iterations
                int idx = lane + u * 64;
                float4 va0 = a0[idx], va1 = a1[idx];
                float4 vb0 = b0[idx], vb1 = b1[idx];
                s00 += fabsf(va0.x - vb0.x) + fabsf(va0.y - vb0.y)
                     + fabsf(va0.z - vb0.z) + fabsf(va0.w - vb0.w);
                s01 += fabsf(va0.x - vb1.x) + fabsf(va0.y - vb1.y)
                     + fabsf(va0.z - vb1.z) + fabsf(va0.w - vb1.w);
                s10 += fabsf(va1.x - vb0.x) + fabsf(va1.y - vb0.y)
                     + fabsf(va1.z - vb0.z) + fabsf(va1.w - vb0.w);
                s11 += fabsf(va1.x - vb1.x) + fabsf(va1.y - vb1.y)
                     + fabsf(va1.z - vb1.z) + fabsf(va1.w - vb1.w);
            }
            #pragma unroll
            for (int o = 32; o > 0; o >>= 1) {
                s00 += __shfl_down(s00, o, 64);
                s01 += __shfl_down(s01, o, 64);
                s10 += __shfl_down(s10, o, 64);
                s11 += __shfl_down(s11, o, 64);
            }
            if (lane == 0) {
                bool diag = (ti == tj);
                float w00 = diag ? 1.0f : 2.0f;
                float w01 = 2.0f;
                float w10 = diag ? 0.0f : 2.0f;
                float w11 = diag ? 1.0f : 2.0f;
                float inv_n = 1.0f / N;
                float d00 = s00 * inv_n - (maxv - zcos[r0 * B + c0]);
                float d01 = s01 * inv_n - (maxv - zcos[r0 * B + c1]);
                float d10 = s10 * inv_n - (maxv - zcos[r1 * B + c0]);
                float d11 = s11 * inv_n - (maxv - zcos[r1 * B + c1]);
                acc += w00 * d00 * d00 + w01 * d01 * d01
                     + w10 * d10 * d10 + w11 * d11 * d11;
            }
        }
        if (lane == 0) partial[w] = acc;
        __syncthreads();
        if (tid == 0) {
            float blk = partial[0] + partial[1] + partial[2] + partial[3]
                      + partial[4] + partial[5] + partial[6] + partial[7];
            atomicAdd(out, blk * (1.0f / (B * B)));
        }
    }
}

extern "C" void kernel_launch(void* const* d_in, const int* in_sizes, int n_in,
                              void* d_out, int out_size, void* d_ws, size_t ws_size,
                              hipStream_t stream) {
    const float* z = (const float*)d_in[0];   // [128,128]
    const float* x = (const float*)d_in[1];   // [128,3,32,32]
    float* out = (float*)d_out;               // [1]
    float* ws = (float*)d_ws;

    float* zcos = ws;                         // 16384 floats
    float* xs   = ws + 16384;                 // 393216 floats

    void* args[] = {(void*)&x, (void*)&z, (void*)&xs, (void*)&zcos, (void*)&out};
    hipLaunchCooperativeKernel((const void*)fused_kernel, dim3(GRID), dim3(NTHREADS),
                               args, 0, stream);
}

// Round 3
// 99.613 us; speedup vs baseline: 1.4514x; 1.4514x over previous
//
#include <hip/hip_runtime.h>
#include <float.h>
#include <math.h>

#define B 128
#define D 128
#define N 3072      // 3*32*32
#define NP1 2048    // half-row sort size (pow2)
#define TROW 64     // row-tiles (2 rows each)
#define NTILE (TROW*(TROW+1)/2)   // 2080 upper-tri 2x2 tiles
#define GRID 256
#define NTHREADS 512

__device__ __forceinline__ void cas(float& a, float& b, bool up) {
    float lo = fminf(a, b), hi = fmaxf(a, b);
    a = up ? lo : hi;
    b = up ? hi : lo;
}

// Monotonic ticket barrier in a __device__ global (survives workspace
// re-poison; never needs reset — each barrier instance consumes GRID
// tickets and waits for the counter to reach the next multiple of GRID).
// Deadlock-free WITHOUT cooperative launch because __launch_bounds__(512,4)
// caps VGPR at 128 -> 16 waves/CU -> 2 blocks/CU capacity -> all 256 blocks
// co-resident at dispatch.
__device__ unsigned g_bar = 0;

__device__ __forceinline__ void gbarrier() {
    __syncthreads();
    if (threadIdx.x == 0) {
        unsigned ticket = __hip_atomic_fetch_add(&g_bar, 1u, __ATOMIC_RELEASE,
                                                 __HIP_MEMORY_SCOPE_AGENT);
        unsigned target = (ticket / GRID + 1u) * GRID;
        while (__hip_atomic_load(&g_bar, __ATOMIC_RELAXED,
                                 __HIP_MEMORY_SCOPE_AGENT) < target) {
            __builtin_amdgcn_s_sleep(2);
        }
        // acquire: invalidate this CU's caches so the whole block sees
        // remote XCDs' xs writes
        (void)__hip_atomic_load(&g_bar, __ATOMIC_ACQUIRE,
                                __HIP_MEMORY_SCOPE_AGENT);
    }
    __syncthreads();
}

// ---------------------------------------------------------------------------
// Fused kernel: 256 blocks x 512 threads (validated R2 phase code, hand
// barrier instead of cg::grid_sync).
// Phase 0: block b sorts half (row=b>>1, half=b&1); half0 DESC, half1 ASC.
// Phase 1: zcos distributed (64 entries per block) + out zero.
// Phase 2: split bitonic merge (j=2048 half-cleaner on load, then 2048 merge).
// Phase 3: pair tiles (validated math), waves grid-stride 2080 tiles.
// ---------------------------------------------------------------------------
__global__ __launch_bounds__(NTHREADS, 4) void fused_kernel(const float* __restrict__ x,
                                                            const float* __restrict__ z,
                                                            float* __restrict__ xs,
                                                            float* __restrict__ zcos,
                                                            float* __restrict__ out) {
    __shared__ float smem[NP1];
    __shared__ float mx[2];
    __shared__ float partial[8];

    int tid = threadIdx.x;
    int bid = blockIdx.x;
    int row  = bid >> 1;      // x-row / z-row
    int half = bid & 1;

    // ---------------- phase 0: sort one 2048-half (validated) -------------
    {
        bool flip = (half == 0);          // half0 descending, half1 ascending
        int lbase = tid * 4;              // local index in [0, 2048)
        int gbase = half * NP1 + lbase;   // global index in row's 4096 space
        float v[4];

        if (gbase < N) {
            float4 t4 = *(const float4*)(x + (size_t)row * N + gbase);
            v[0] = t4.x; v[1] = t4.y; v[2] = t4.z; v[3] = t4.w;
        } else {
            v[0] = v[1] = v[2] = v[3] = FLT_MAX;
        }

        for (int k = 2; k <= NP1; k <<= 1) {
            int j = k >> 1;
            bool ub = (((lbase & k) == 0) != flip);

            if (j >= 256) {
                ((float4*)smem)[tid] = make_float4(v[0], v[1], v[2], v[3]);
                __syncthreads();
                for (; j >= 256; j >>= 1) {
                    #pragma unroll
                    for (int u = 0; u < 2; u++) {
                        int p = tid + u * 512;          // 1024 pairs per pass
                        int i = ((p & ~(j - 1)) << 1) | (p & (j - 1));
                        int pj = i | j;
                        float a = smem[i], b2 = smem[pj];
                        bool up = (((i & k) == 0) != flip);
                        if ((a > b2) == up) { smem[i] = b2; smem[pj] = a; }
                    }
                    __syncthreads();
                }
                float4 t4 = ((float4*)smem)[tid];
                v[0] = t4.x; v[1] = t4.y; v[2] = t4.z; v[3] = t4.w;
                __syncthreads();
            }

            for (; j >= 4; j >>= 1) {
                int lx = j >> 2;
                bool keep_lower = ((tid & lx) == 0);
                bool sel = (keep_lower == ub);
                #pragma unroll
                for (int r = 0; r < 4; r++) {
                    float p = __shfl_xor(v[r], lx, 64);
                    v[r] = sel ? fminf(v[r], p) : fmaxf(v[r], p);
                }
            }
            if (j == 2) {
                cas(v[0], v[2], ub);
                cas(v[1], v[3], ub);
                j >>= 1;
            }
            {
                bool upA = ((((lbase + 0) & k) == 0) != flip);
                bool upB = ((((lbase + 2) & k) == 0) != flip);
                cas(v[0], v[1], upA);
                cas(v[2], v[3], upB);
            }
        }

        if (gbase < N)
            *(float4*)(xs + (size_t)row * N + gbase) = make_float4(v[0], v[1], v[2], v[3]);
    }
    __syncthreads();

    // ---------------- phase 1: zcos (64 entries) + out zero ---------------
    {
        // all-row inverse norms into smem[0..127] (4 threads per row)
        int r2 = tid >> 2;
        int seg = tid & 3;
        const float4* zr = (const float4*)(z + r2 * D + seg * 32);
        float s = 0.f;
        #pragma unroll
        for (int u = 0; u < 8; u++) {
            float4 vv = zr[u];
            s += vv.x * vv.x + vv.y * vv.y + vv.z * vv.z + vv.w * vv.w;
        }
        s += __shfl_down(s, 2, 4);
        s += __shfl_down(s, 1, 4);
        if (seg == 0) smem[r2] = 1.0f / fmaxf(sqrtf(s), 1e-12f);
        __syncthreads();

        // 64 entries: (row, half*64 + e), 8 threads per entry
        int e  = tid >> 3;
        int sg = tid & 7;
        int j  = half * 64 + e;
        const float4* zi = (const float4*)(z + row * D + sg * 16);
        const float4* zj = (const float4*)(z + j * D + sg * 16);
        float dot = 0.f;
        #pragma unroll
        for (int u = 0; u < 4; u++) {
            float4 a = zi[u], b = zj[u];
            dot += a.x * b.x + a.y * b.y + a.z * b.z + a.w * b.w;
        }
        dot += __shfl_down(dot, 4, 8);
        dot += __shfl_down(dot, 2, 8);
        dot += __shfl_down(dot, 1, 8);
        if (sg == 0) zcos[row * B + j] = dot * smem[row] * smem[j];

        if (bid == 0 && tid == 0) out[0] = 0.f;
    }

    gbarrier();

    // ---------------- phase 2: split bitonic merge (ascending) ------------
    {
        int lbase = tid * 4;
        const float4* xr = (const float4*)(xs + (size_t)row * N);
        float v[4];

        if (half == 0) {
            // L half: min(s_i, s_{i+2048}); partner is FLT_MAX for i>=1024
            float4 a = xr[tid];
            if (lbase < 1024) {
                float4 c = xr[tid + 512];
                v[0] = fminf(a.x, c.x); v[1] = fminf(a.y, c.y);
                v[2] = fminf(a.z, c.z); v[3] = fminf(a.w, c.w);
            } else {
                v[0] = a.x; v[1] = a.y; v[2] = a.z; v[3] = a.w;
            }
        } else {
            // H half: max(s_i, s_{i+2048}) for i<1024, FLT_MAX above
            if (lbase < 1024) {
                float4 a = xr[tid];
                float4 c = xr[tid + 512];
                v[0] = fmaxf(a.x, c.x); v[1] = fmaxf(a.y, c.y);
                v[2] = fmaxf(a.z, c.z); v[3] = fmaxf(a.w, c.w);
            } else {
                v[0] = v[1] = v[2] = v[3] = FLT_MAX;
            }
        }

        ((float4*)smem)[tid] = make_float4(v[0], v[1], v[2], v[3]);
        __syncthreads();
        for (int j = 1024; j >= 256; j >>= 1) {
            #pragma unroll
            for (int u = 0; u < 2; u++) {
                int p = tid + u * 512;
                int i = ((p & ~(j - 1)) << 1) | (p & (j - 1));
                int pj = i | j;
                float a = smem[i], b2 = smem[pj];
                if (a > b2) { smem[i] = b2; smem[pj] = a; }   // ascending
            }
            __syncthreads();
        }
        {
            float4 t4 = ((float4*)smem)[tid];
            v[0] = t4.x; v[1] = t4.y; v[2] = t4.z; v[3] = t4.w;
        }
        for (int j = 128; j >= 4; j >>= 1) {
            int lx = j >> 2;
            bool sel = ((tid & lx) == 0);
            #pragma unroll
            for (int r = 0; r < 4; r++) {
                float p = __shfl_xor(v[r], lx, 64);
                v[r] = sel ? fminf(v[r], p) : fmaxf(v[r], p);
            }
        }
        cas(v[0], v[2], true);
        cas(v[1], v[3], true);
        cas(v[0], v[1], true);
        cas(v[2], v[3], true);

        int gbase = half * NP1 + lbase;
        if (gbase < N)
            *(float4*)(xs + (size_t)row * N + gbase) = make_float4(v[0], v[1], v[2], v[3]);
    }

    gbarrier();

    // ---------------- phase 3: pair tiles (validated math) ----------------
    {
        if (tid < B) {
            float vv = zcos[tid * (B + 1)];
            #pragma unroll
            for (int o = 32; o > 0; o >>= 1) vv = fmaxf(vv, __shfl_down(vv, o, 64));
            if ((tid & 63) == 0) mx[tid >> 6] = vv;
        }
        __syncthreads();
        float maxv = fmaxf(mx[0], mx[1]);

        int w = tid >> 6;                  // wave 0..7
        int lane = tid & 63;
        float acc = 0.f;

        for (int T = bid * 8 + w; T < NTILE; T += GRID * 8) {
            // decode T -> (ti, tj), ti<=tj over TROW=64 (validated decode)
            float ff = (float)(2 * TROW + 1);
            int ti = (int)((ff - sqrtf(ff * ff - 8.0f * (float)T)) * 0.5f);
            if (ti < 0) ti = 0;
            if (ti > TROW - 1) ti = TROW - 1;
            while ((ti + 1) * TROW - ((ti + 1) * ti) / 2 <= T) ti++;
            while (ti * TROW - (ti * (ti - 1)) / 2 > T) ti--;
            int tj = ti + (T - (ti * TROW - (ti * (ti - 1)) / 2));

            int r0 = 2 * ti, r1 = r0 + 1;
            int c0 = 2 * tj, c1 = c0 + 1;

            const float4* a0 = (const float4*)(xs + (size_t)r0 * N);
            const float4* a1 = (const float4*)(xs + (size_t)r1 * N);
            const float4* b0 = (const float4*)(xs + (size_t)c0 * N);
            const float4* b1 = (const float4*)(xs + (size_t)c1 * N);

            float s00 = 0.f, s01 = 0.f, s10 = 0.f, s11 = 0.f;
            #pragma unroll
            for (int u = 0; u < N / 4 / 64; u++) {          // 12 iterations
                int idx = lane + u * 64;
                float4 va0 = a0[idx], va1 = a1[idx];
                float4 vb0 = b0[idx], vb1 = b1[idx];
                s00 += fabsf(va0.x - vb0.x) + fabsf(va0.y - vb0.y)
                     + fabsf(va0.z - vb0.z) + fabsf(va0.w - vb0.w);
                s01 += fabsf(va0.x - vb1.x) + fabsf(va0.y - vb1.y)
                     + fabsf(va0.z - vb1.z) + fabsf(va0.w - vb1.w);
                s10 += fabsf(va1.x - vb0.x) + fabsf(va1.y - vb0.y)
                     + fabsf(va1.z - vb0.z) + fabsf(va1.w - vb0.w);
                s11 += fabsf(va1.x - vb1.x) + fabsf(va1.y - vb1.y)
                     + fabsf(va1.z - vb1.z) + fabsf(va1.w - vb1.w);
            }
            #pragma unroll
            for (int o = 32; o > 0; o >>= 1) {
                s00 += __shfl_down(s00, o, 64);
                s01 += __shfl_down(s01, o, 64);
                s10 += __shfl_down(s10, o, 64);
                s11 += __shfl_down(s11, o, 64);
            }
            if (lane == 0) {
                bool diag = (ti == tj);
                float w00 = diag ? 1.0f : 2.0f;
                float w01 = 2.0f;
                float w10 = diag ? 0.0f : 2.0f;
                float w11 = diag ? 1.0f : 2.0f;
                float inv_n = 1.0f / N;
                float d00 = s00 * inv_n - (maxv - zcos[r0 * B + c0]);
                float d01 = s01 * inv_n - (maxv - zcos[r0 * B + c1]);
                float d10 = s10 * inv_n - (maxv - zcos[r1 * B + c0]);
                float d11 = s11 * inv_n - (maxv - zcos[r1 * B + c1]);
                acc += w00 * d00 * d00 + w01 * d01 * d01
                     + w10 * d10 * d10 + w11 * d11 * d11;
            }
        }
        if (lane == 0) partial[w] = acc;
        __syncthreads();
        if (tid == 0) {
            float blk = partial[0] + partial[1] + partial[2] + partial[3]
                      + partial[4] + partial[5] + partial[6] + partial[7];
            atomicAdd(out, blk * (1.0f / (B * B)));
        }
    }
}

extern "C" void kernel_launch(void* const* d_in, const int* in_sizes, int n_in,
                              void* d_out, int out_size, void* d_ws, size_t ws_size,
                              hipStream_t stream) {
    const float* z = (const float*)d_in[0];   // [128,128]
    const float* x = (const float*)d_in[1];   // [128,3,32,32]
    float* out = (float*)d_out;               // [1]
    float* ws = (float*)d_ws;

    float* zcos = ws;                         // 16384 floats
    float* xs   = ws + 16384;                 // 393216 floats

    fused_kernel<<<GRID, NTHREADS, 0, stream>>>(x, z, xs, zcos, out);
}

// Round 4
// 90.820 us; speedup vs baseline: 1.5920x; 1.0968x over previous
//
#include <hip/hip_runtime.h>
#include <float.h>
#include <math.h>

#define B 128
#define D 128
#define N 3072      // 3*32*32
#define NP1 2048    // half-row sort size (pow2)
#define TROW 64     // row-tiles (2 rows each)
#define NTILE (TROW*(TROW+1)/2)   // 2080 upper-tri 2x2 tiles
#define GRID 256
#define NTHREADS 512

__device__ __forceinline__ void cas(float& a, float& b, bool up) {
    float lo = fminf(a, b), hi = fmaxf(a, b);
    a = up ? lo : hi;
    b = up ? hi : lo;
}

// Cross-XCD data movement WITHOUT cache maintenance: relaxed agent-scope
// atomics compile to coherent (sc-bit) loads/stores that bypass the
// non-coherent per-XCD L2s — no buffer_wbl2/buffer_inv is ever emitted.
__device__ __forceinline__ void st_agent_f2(float* p, float a, float b) {
    union { float f[2]; unsigned long long u; } t;
    t.f[0] = a; t.f[1] = b;
    __hip_atomic_store((unsigned long long*)p, t.u, __ATOMIC_RELAXED,
                       __HIP_MEMORY_SCOPE_AGENT);
}
__device__ __forceinline__ float2 ld_agent_f2(const float* p) {
    unsigned long long u = __hip_atomic_load((const unsigned long long*)p,
                                             __ATOMIC_RELAXED,
                                             __HIP_MEMORY_SCOPE_AGENT);
    union { unsigned long long u; float f[2]; } t; t.u = u;
    return make_float2(t.f[0], t.f[1]);
}

// Monotonic ticket barrier, FULLY RELAXED (no acquire/release -> no L2
// flush/invalidate). Visibility of data is guaranteed because all
// cross-block data uses agent-scope (L2-bypassing) loads/stores, and each
// wave drains vmcnt(0) before arriving (store-ack = at coherent point).
// Survives workspace re-poison (device global, monotonic — never reset).
// Deadlock-free without cooperative launch: __launch_bounds__(512,4) caps
// VGPR at 128 -> >=2 blocks/CU capacity -> all 256 blocks co-resident.
__device__ unsigned g_bar = 0;

__device__ __forceinline__ void gbarrier() {
    asm volatile("s_waitcnt vmcnt(0)" ::: "memory");  // per-wave store drain
    __syncthreads();
    if (threadIdx.x == 0) {
        unsigned t = __hip_atomic_fetch_add(&g_bar, 1u, __ATOMIC_RELAXED,
                                            __HIP_MEMORY_SCOPE_AGENT);
        unsigned target = (t / GRID + 1u) * GRID;
        while (__hip_atomic_load(&g_bar, __ATOMIC_RELAXED,
                                 __HIP_MEMORY_SCOPE_AGENT) < target) {
            __builtin_amdgcn_s_sleep(4);
        }
    }
    __syncthreads();
}

// ---------------------------------------------------------------------------
// Fused kernel: 256 blocks x 512 threads.
// Phase 0: block b sorts half (row=b>>1, half=b&1); half0 DESC, half1 ASC
//          -> concatenation is a valley bitonic sequence. Writes xs via
//          agent stores (coherent point).
// Phase 1: zcos distributed (64 entries/block, agent stores) + out zero.
// Phase 2: split bitonic merge; reads xs via agent loads, writes MERGED
//          output to xs2 (separate buffer!) via agent stores. xs2 lines are
//          never L2-cached before phase 3 -> phase 3 may use plain cached
//          loads with no staleness risk, independent of XCD placement.
// Phase 3: pair tiles (validated math), plain (L2-cacheable) reads of xs2.
// ---------------------------------------------------------------------------
__global__ __launch_bounds__(NTHREADS, 4) void fused_kernel(const float* __restrict__ x,
                                                            const float* __restrict__ z,
                                                            float* __restrict__ xs,
                                                            float* __restrict__ xs2,
                                                            float* __restrict__ zcos,
                                                            float* __restrict__ out) {
    __shared__ float smem[NP1];
    __shared__ float mx[2];
    __shared__ float partial[8];

    int tid = threadIdx.x;
    int bid = blockIdx.x;
    int row  = bid >> 1;      // x-row / z-row
    int half = bid & 1;

    // ---------------- phase 0: sort one 2048-half (validated) -------------
    {
        bool flip = (half == 0);          // half0 descending, half1 ascending
        int lbase = tid * 4;              // local index in [0, 2048)
        int gbase = half * NP1 + lbase;   // global index in row's 4096 space
        float v[4];

        if (gbase < N) {
            float4 t4 = *(const float4*)(x + (size_t)row * N + gbase);
            v[0] = t4.x; v[1] = t4.y; v[2] = t4.z; v[3] = t4.w;
        } else {
            v[0] = v[1] = v[2] = v[3] = FLT_MAX;
        }

        for (int k = 2; k <= NP1; k <<= 1) {
            int j = k >> 1;
            bool ub = (((lbase & k) == 0) != flip);

            if (j >= 256) {
                ((float4*)smem)[tid] = make_float4(v[0], v[1], v[2], v[3]);
                __syncthreads();
                for (; j >= 256; j >>= 1) {
                    #pragma unroll
                    for (int u = 0; u < 2; u++) {
                        int p = tid + u * 512;          // 1024 pairs per pass
                        int i = ((p & ~(j - 1)) << 1) | (p & (j - 1));
                        int pj = i | j;
                        float a = smem[i], b2 = smem[pj];
                        bool up = (((i & k) == 0) != flip);
                        if ((a > b2) == up) { smem[i] = b2; smem[pj] = a; }
                    }
                    __syncthreads();
                }
                float4 t4 = ((float4*)smem)[tid];
                v[0] = t4.x; v[1] = t4.y; v[2] = t4.z; v[3] = t4.w;
                __syncthreads();
            }

            for (; j >= 4; j >>= 1) {
                int lx = j >> 2;
                bool keep_lower = ((tid & lx) == 0);
                bool sel = (keep_lower == ub);
                #pragma unroll
                for (int r = 0; r < 4; r++) {
                    float p = __shfl_xor(v[r], lx, 64);
                    v[r] = sel ? fminf(v[r], p) : fmaxf(v[r], p);
                }
            }
            if (j == 2) {
                cas(v[0], v[2], ub);
                cas(v[1], v[3], ub);
                j >>= 1;
            }
            {
                bool upA = ((((lbase + 0) & k) == 0) != flip);
                bool upB = ((((lbase + 2) & k) == 0) != flip);
                cas(v[0], v[1], upA);
                cas(v[2], v[3], upB);
            }
        }

        if (gbase < N) {
            float* dst = xs + (size_t)row * N + gbase;
            st_agent_f2(dst, v[0], v[1]);
            st_agent_f2(dst + 2, v[2], v[3]);
        }
    }
    __syncthreads();

    // ---------------- phase 1: zcos (64 entries) + out zero ---------------
    {
        // all-row inverse norms into smem[0..127] (4 threads per row)
        int r2 = tid >> 2;
        int seg = tid & 3;
        const float4* zr = (const float4*)(z + r2 * D + seg * 32);
        float s = 0.f;
        #pragma unroll
        for (int u = 0; u < 8; u++) {
            float4 vv = zr[u];
            s += vv.x * vv.x + vv.y * vv.y + vv.z * vv.z + vv.w * vv.w;
        }
        s += __shfl_down(s, 2, 4);
        s += __shfl_down(s, 1, 4);
        if (seg == 0) smem[r2] = 1.0f / fmaxf(sqrtf(s), 1e-12f);
        __syncthreads();

        // 64 entries: (row, half*64 + e), 8 threads per entry
        int e  = tid >> 3;
        int sg = tid & 7;
        int j  = half * 64 + e;
        const float4* zi = (const float4*)(z + row * D + sg * 16);
        const float4* zj = (const float4*)(z + j * D + sg * 16);
        float dot = 0.f;
        #pragma unroll
        for (int u = 0; u < 4; u++) {
            float4 a = zi[u], b = zj[u];
            dot += a.x * b.x + a.y * b.y + a.z * b.z + a.w * b.w;
        }
        dot += __shfl_down(dot, 4, 8);
        dot += __shfl_down(dot, 2, 8);
        dot += __shfl_down(dot, 1, 8);
        if (sg == 0) {
            __hip_atomic_store(&zcos[row * B + j], dot * smem[row] * smem[j],
                               __ATOMIC_RELAXED, __HIP_MEMORY_SCOPE_AGENT);
        }

        if (bid == 0 && tid == 0) {
            __hip_atomic_store(out, 0.f, __ATOMIC_RELAXED,
                               __HIP_MEMORY_SCOPE_AGENT);
        }
    }

    gbarrier();

    // ---------------- phase 2: split bitonic merge (ascending) ------------
    // xs read via agent loads (coherent); merged result -> xs2 (agent stores)
    {
        int lbase = tid * 4;
        const float* xr = xs + (size_t)row * N;
        float v[4];

        if (half == 0) {
            // L half: min(s_i, s_{i+2048}); partner is FLT_MAX for i>=1024
            float2 a01 = ld_agent_f2(xr + lbase);
            float2 a23 = ld_agent_f2(xr + lbase + 2);
            if (lbase < 1024) {
                float2 c01 = ld_agent_f2(xr + lbase + 2048);
                float2 c23 = ld_agent_f2(xr + lbase + 2050);
                v[0] = fminf(a01.x, c01.x); v[1] = fminf(a01.y, c01.y);
                v[2] = fminf(a23.x, c23.x); v[3] = fminf(a23.y, c23.y);
            } else {
                v[0] = a01.x; v[1] = a01.y; v[2] = a23.x; v[3] = a23.y;
            }
        } else {
            // H half: max(s_i, s_{i+2048}) for i<1024, FLT_MAX above
            if (lbase < 1024) {
                float2 a01 = ld_agent_f2(xr + lbase);
                float2 a23 = ld_agent_f2(xr + lbase + 2);
                float2 c01 = ld_agent_f2(xr + lbase + 2048);
                float2 c23 = ld_agent_f2(xr + lbase + 2050);
                v[0] = fmaxf(a01.x, c01.x); v[1] = fmaxf(a01.y, c01.y);
                v[2] = fmaxf(a23.x, c23.x); v[3] = fmaxf(a23.y, c23.y);
            } else {
                v[0] = v[1] = v[2] = v[3] = FLT_MAX;
            }
        }

        ((float4*)smem)[tid] = make_float4(v[0], v[1], v[2], v[3]);
        __syncthreads();
        for (int j = 1024; j >= 256; j >>= 1) {
            #pragma unroll
            for (int u = 0; u < 2; u++) {
                int p = tid + u * 512;
                int i = ((p & ~(j - 1)) << 1) | (p & (j - 1));
                int pj = i | j;
                float a = smem[i], b2 = smem[pj];
                if (a > b2) { smem[i] = b2; smem[pj] = a; }   // ascending
            }
            __syncthreads();
        }
        {
            float4 t4 = ((float4*)smem)[tid];
            v[0] = t4.x; v[1] = t4.y; v[2] = t4.z; v[3] = t4.w;
        }
        for (int j = 128; j >= 4; j >>= 1) {
            int lx = j >> 2;
            bool sel = ((tid & lx) == 0);
            #pragma unroll
            for (int r = 0; r < 4; r++) {
                float p = __shfl_xor(v[r], lx, 64);
                v[r] = sel ? fminf(v[r], p) : fmaxf(v[r], p);
            }
        }
        cas(v[0], v[2], true);
        cas(v[1], v[3], true);
        cas(v[0], v[1], true);
        cas(v[2], v[3], true);

        int gbase = half * NP1 + lbase;
        if (gbase < N) {
            float* dst = xs2 + (size_t)row * N + gbase;
            st_agent_f2(dst, v[0], v[1]);
            st_agent_f2(dst + 2, v[2], v[3]);
        }
    }

    gbarrier();

    // ---------------- phase 3: pair tiles (validated math) ----------------
    // Plain cached reads of xs2/zcos: safe — no L2 ever held these lines
    // before this point (all prior accesses bypassed L2).
    {
        if (tid < B) {
            float vv = zcos[tid * (B + 1)];
            #pragma unroll
            for (int o = 32; o > 0; o >>= 1) vv = fmaxf(vv, __shfl_down(vv, o, 64));
            if ((tid & 63) == 0) mx[tid >> 6] = vv;
        }
        __syncthreads();
        float maxv = fmaxf(mx[0], mx[1]);

        int w = tid >> 6;                  // wave 0..7
        int lane = tid & 63;
        float acc = 0.f;

        // 2048 primary tiles (one per wave) + 32 leftovers spread across 32
        // DIFFERENT blocks (wave 0 of every 8th block) for balance.
        int nT = (w == 0 && (bid & 7) == 0) ? 2 : 1;
        for (int pass = 0; pass < nT; ++pass) {
            int T = (pass == 0) ? (bid * 8 + w) : (2048 + (bid >> 3));

            // decode T -> (ti, tj), ti<=tj over TROW=64 (validated decode)
            float ff = (float)(2 * TROW + 1);
            int ti = (int)((ff - sqrtf(ff * ff - 8.0f * (float)T)) * 0.5f);
            if (ti < 0) ti = 0;
            if (ti > TROW - 1) ti = TROW - 1;
            while ((ti + 1) * TROW - ((ti + 1) * ti) / 2 <= T) ti++;
            while (ti * TROW - (ti * (ti - 1)) / 2 > T) ti--;
            int tj = ti + (T - (ti * TROW - (ti * (ti - 1)) / 2));

            int r0 = 2 * ti, r1 = r0 + 1;
            int c0 = 2 * tj, c1 = c0 + 1;

            const float4* a0 = (const float4*)(xs2 + (size_t)r0 * N);
            const float4* a1 = (const float4*)(xs2 + (size_t)r1 * N);
            const float4* b0 = (const float4*)(xs2 + (size_t)c0 * N);
            const float4* b1 = (const float4*)(xs2 + (size_t)c1 * N);

            float s00 = 0.f, s01 = 0.f, s10 = 0.f, s11 = 0.f;
            #pragma unroll
            for (int u = 0; u < N / 4 / 64; u++) {          // 12 iterations
                int idx = lane + u * 64;
                float4 va0 = a0[idx], va1 = a1[idx];
                float4 vb0 = b0[idx], vb1 = b1[idx];
                s00 += fabsf(va0.x - vb0.x) + fabsf(va0.y - vb0.y)
                     + fabsf(va0.z - vb0.z) + fabsf(va0.w - vb0.w);
                s01 += fabsf(va0.x - vb1.x) + fabsf(va0.y - vb1.y)
                     + fabsf(va0.z - vb1.z) + fabsf(va0.w - vb1.w);
                s10 += fabsf(va1.x - vb0.x) + fabsf(va1.y - vb0.y)
                     + fabsf(va1.z - vb0.z) + fabsf(va1.w - vb0.w);
                s11 += fabsf(va1.x - vb1.x) + fabsf(va1.y - vb1.y)
                     + fabsf(va1.z - vb1.z) + fabsf(va1.w - vb1.w);
            }
            #pragma unroll
            for (int o = 32; o > 0; o >>= 1) {
                s00 += __shfl_down(s00, o, 64);
                s01 += __shfl_down(s01, o, 64);
                s10 += __shfl_down(s10, o, 64);
                s11 += __shfl_down(s11, o, 64);
            }
            if (lane == 0) {
                bool diag = (ti == tj);
                float w00 = diag ? 1.0f : 2.0f;
                float w01 = 2.0f;
                float w10 = diag ? 0.0f : 2.0f;
                float w11 = diag ? 1.0f : 2.0f;
                float inv_n = 1.0f / N;
                float d00 = s00 * inv_n - (maxv - zcos[r0 * B + c0]);
                float d01 = s01 * inv_n - (maxv - zcos[r0 * B + c1]);
                float d10 = s10 * inv_n - (maxv - zcos[r1 * B + c0]);
                float d11 = s11 * inv_n - (maxv - zcos[r1 * B + c1]);
                acc += w00 * d00 * d00 + w01 * d01 * d01
                     + w10 * d10 * d10 + w11 * d11 * d11;
            }
        }
        if (lane == 0) partial[w] = acc;
        __syncthreads();
        if (tid == 0) {
            float blk = partial[0] + partial[1] + partial[2] + partial[3]
                      + partial[4] + partial[5] + partial[6] + partial[7];
            atomicAdd(out, blk * (1.0f / (B * B)));
        }
    }
}

extern "C" void kernel_launch(void* const* d_in, const int* in_sizes, int n_in,
                              void* d_out, int out_size, void* d_ws, size_t ws_size,
                              hipStream_t stream) {
    const float* z = (const float*)d_in[0];   // [128,128]
    const float* x = (const float*)d_in[1];   // [128,3,32,32]
    float* out = (float*)d_out;               // [1]
    float* ws = (float*)d_ws;

    float* zcos = ws;                         // 16384 floats
    float* xs   = ws + 16384;                 // 393216 floats (sorted halves)
    float* xs2  = ws + 16384 + 393216;        // 393216 floats (merged rows)

    fused_kernel<<<GRID, NTHREADS, 0, stream>>>(x, z, xs, xs2, zcos, out);
}

// Round 5
// 85.852 us; speedup vs baseline: 1.6841x; 1.0579x over previous
//
#include <hip/hip_runtime.h>
#include <float.h>
#include <math.h>

#define B 128
#define D 128
#define N 3072      // 3*32*32
#define NP1 2048    // half-row sort size (pow2)
#define TROW 64     // row-tiles (2 rows each)
#define NTILE (TROW*(TROW+1)/2)   // 2080 upper-tri 2x2 tiles
#define GRID 256
#define NTHREADS 512

__device__ __forceinline__ void cas(float& a, float& b, bool up) {
    float lo = fminf(a, b), hi = fmaxf(a, b);
    a = up ? lo : hi;
    b = up ? hi : lo;
}

// Cross-XCD data movement WITHOUT cache maintenance: relaxed agent-scope
// atomic stores compile to coherent (sc-bit) stores that bypass the
// non-coherent per-XCD L2s; readers' first CACHED read of any such line
// happens only after the writer's flag -> no staleness, no wb/inv ever.
__device__ __forceinline__ void st_agent_f2(float* p, float a, float b) {
    union { float f[2]; unsigned long long u; } t;
    t.f[0] = a; t.f[1] = b;
    __hip_atomic_store((unsigned long long*)p, t.u, __ATOMIC_RELAXED,
                       __HIP_MEMORY_SCOPE_AGENT);
}

// Monotonic per-block generation flags (device globals: zero at load, never
// reset; every launch increments each exactly once -> generation number n is
// globally consistent across iterations and rocprof replays).
// NO grid-wide barrier anywhere: waits follow the true dependency graph.
// Deadlock-free without cooperative launch: __launch_bounds__(512,4) caps
// VGPR at 128 -> >=2 blocks/CU capacity -> all 256 blocks co-resident.
__device__ unsigned g_half[GRID];    // set after phase 0+1 stores drained
__device__ unsigned g_merge[GRID];   // set after phase 2 stores drained
__device__ unsigned g_outz;          // set after out[0]=0 drained (block 0)

__device__ __forceinline__ unsigned ld_flag(const unsigned* p) {
    return __hip_atomic_load(p, __ATOMIC_RELAXED, __HIP_MEMORY_SCOPE_AGENT);
}

// ---------------------------------------------------------------------------
// Fused kernel, 256 blocks x 512 threads, point-to-point sync only.
// Phase 0: block b sorts half (row=b>>1, half=b&1); half0 DESC, half1 ASC
//          -> concatenation is a valley bitonic sequence (validated).
// Phase 1: zcos (64 entries/block, agent stores) + LOCAL diag recompute
//          (bit-identical arithmetic) so maxv needs no cross-block wait.
// sync A:  pairwise — wait g_half[bid^1] only.
// Phase 2: split bitonic merge (cached float4 reads of xs; agent stores xs2).
// sync B:  per-tile — wait g_merge[4ti..4ti+3, 4tj..4tj+3] (8 flags).
// Phase 3: pair tiles (validated math), cached reads of xs2/zcos.
// ---------------------------------------------------------------------------
__global__ __launch_bounds__(NTHREADS, 4) void fused_kernel(const float* __restrict__ x,
                                                            const float* __restrict__ z,
                                                            float* __restrict__ xs,
                                                            float* __restrict__ xs2,
                                                            float* __restrict__ zcos,
                                                            float* __restrict__ out) {
    __shared__ float smem[NP1];
    __shared__ float inv_s[B];
    __shared__ float diag[B];
    __shared__ float partial[8];
    __shared__ float s_maxv;
    __shared__ unsigned sgen;

    int tid = threadIdx.x;
    int bid = blockIdx.x;
    int row  = bid >> 1;      // x-row / z-row
    int half = bid & 1;

    // out zero, flagged (block 0 only, before anything else)
    if (bid == 0 && tid == 0) {
        __hip_atomic_store(out, 0.f, __ATOMIC_RELAXED, __HIP_MEMORY_SCOPE_AGENT);
        asm volatile("s_waitcnt vmcnt(0)" ::: "memory");
        __hip_atomic_fetch_add(&g_outz, 1u, __ATOMIC_RELAXED,
                               __HIP_MEMORY_SCOPE_AGENT);
    }

    // ---------------- phase 0: sort one 2048-half (validated) -------------
    {
        bool flip = (half == 0);          // half0 descending, half1 ascending
        int lbase = tid * 4;              // local index in [0, 2048)
        int gbase = half * NP1 + lbase;   // global index in row's 4096 space
        float v[4];

        if (gbase < N) {
            float4 t4 = *(const float4*)(x + (size_t)row * N + gbase);
            v[0] = t4.x; v[1] = t4.y; v[2] = t4.z; v[3] = t4.w;
        } else {
            v[0] = v[1] = v[2] = v[3] = FLT_MAX;
        }

        for (int k = 2; k <= NP1; k <<= 1) {
            int j = k >> 1;
            bool ub = (((lbase & k) == 0) != flip);

            if (j >= 256) {
                ((float4*)smem)[tid] = make_float4(v[0], v[1], v[2], v[3]);
                __syncthreads();
                for (; j >= 256; j >>= 1) {
                    #pragma unroll
                    for (int u = 0; u < 2; u++) {
                        int p = tid + u * 512;          // 1024 pairs per pass
                        int i = ((p & ~(j - 1)) << 1) | (p & (j - 1));
                        int pj = i | j;
                        float a = smem[i], b2 = smem[pj];
                        bool up = (((i & k) == 0) != flip);
                        if ((a > b2) == up) { smem[i] = b2; smem[pj] = a; }
                    }
                    __syncthreads();
                }
                float4 t4 = ((float4*)smem)[tid];
                v[0] = t4.x; v[1] = t4.y; v[2] = t4.z; v[3] = t4.w;
                __syncthreads();
            }

            for (; j >= 4; j >>= 1) {
                int lx = j >> 2;
                bool keep_lower = ((tid & lx) == 0);
                bool sel = (keep_lower == ub);
                #pragma unroll
                for (int r = 0; r < 4; r++) {
                    float p = __shfl_xor(v[r], lx, 64);
                    v[r] = sel ? fminf(v[r], p) : fmaxf(v[r], p);
                }
            }
            if (j == 2) {
                cas(v[0], v[2], ub);
                cas(v[1], v[3], ub);
                j >>= 1;
            }
            {
                bool upA = ((((lbase + 0) & k) == 0) != flip);
                bool upB = ((((lbase + 2) & k) == 0) != flip);
                cas(v[0], v[1], upA);
                cas(v[2], v[3], upB);
            }
        }

        if (gbase < N) {
            float* dst = xs + (size_t)row * N + gbase;
            st_agent_f2(dst, v[0], v[1]);
            st_agent_f2(dst + 2, v[2], v[3]);
        }
    }
    __syncthreads();

    // ---------------- phase 1: zcos (64 entries) + local diag -------------
    {
        // all-row inverse norms (4 threads per row) — identical in all blocks
        int r2 = tid >> 2;
        int seg = tid & 3;
        const float4* zr = (const float4*)(z + r2 * D + seg * 32);
        float s = 0.f;
        #pragma unroll
        for (int u = 0; u < 8; u++) {
            float4 vv = zr[u];
            s += vv.x * vv.x + vv.y * vv.y + vv.z * vv.z + vv.w * vv.w;
        }
        s += __shfl_down(s, 2, 4);
        s += __shfl_down(s, 1, 4);
        if (seg == 0) inv_s[r2] = 1.0f / fmaxf(sqrtf(s), 1e-12f);
        __syncthreads();

        // 64 zcos entries: (row, half*64 + e), 8 threads per entry
        int e  = tid >> 3;
        int sg = tid & 7;
        int j  = half * 64 + e;
        {
            const float4* zi = (const float4*)(z + row * D + sg * 16);
            const float4* zj = (const float4*)(z + j * D + sg * 16);
            float dot = 0.f;
            #pragma unroll
            for (int u = 0; u < 4; u++) {
                float4 a = zi[u], b = zj[u];
                dot += a.x * b.x + a.y * b.y + a.z * b.z + a.w * b.w;
            }
            dot += __shfl_down(dot, 4, 8);
            dot += __shfl_down(dot, 2, 8);
            dot += __shfl_down(dot, 1, 8);
            if (sg == 0) {
                __hip_atomic_store(&zcos[row * B + j], dot * inv_s[row] * inv_s[j],
                                   __ATOMIC_RELAXED, __HIP_MEMORY_SCOPE_AGENT);
            }
        }

        // local diag recompute: SAME arithmetic shape as the zcos path
        // (so maxv bits match the written zcos diagonal), 2 rounds of 64
        #pragma unroll
        for (int rep = 0; rep < 2; rep++) {
            int er = e + rep * 64;
            const float4* zi = (const float4*)(z + er * D + sg * 16);
            const float4* zj = (const float4*)(z + er * D + sg * 16);
            float dot = 0.f;
            #pragma unroll
            for (int u = 0; u < 4; u++) {
                float4 a = zi[u], b = zj[u];
                dot += a.x * b.x + a.y * b.y + a.z * b.z + a.w * b.w;
            }
            dot += __shfl_down(dot, 4, 8);
            dot += __shfl_down(dot, 2, 8);
            dot += __shfl_down(dot, 1, 8);
            if (sg == 0) diag[er] = dot * inv_s[er] * inv_s[er];
        }
    }

    // ---------------- sync A: flag own half, wait partner only ------------
    asm volatile("s_waitcnt vmcnt(0)" ::: "memory");   // every wave drains
    __syncthreads();
    if (tid == 0) {
        unsigned g = __hip_atomic_fetch_add(&g_half[bid], 1u, __ATOMIC_RELAXED,
                                            __HIP_MEMORY_SCOPE_AGENT) + 1u;
        sgen = g;
        while (ld_flag(&g_half[bid ^ 1]) < g) __builtin_amdgcn_s_sleep(1);
    }
    __syncthreads();
    unsigned gen = sgen;

    // ---------------- phase 2: split bitonic merge (ascending) ------------
    // cached float4 reads of xs are safe: no xs line was cached pre-flag.
    {
        int lbase = tid * 4;
        const float4* xr4 = (const float4*)(xs + (size_t)row * N);
        float v[4];

        if (half == 0) {
            // L half: min(s_i, s_{i+2048}); partner is FLT_MAX for i>=1024
            float4 a = xr4[tid];
            if (lbase < 1024) {
                float4 c = xr4[tid + 512];
                v[0] = fminf(a.x, c.x); v[1] = fminf(a.y, c.y);
                v[2] = fminf(a.z, c.z); v[3] = fminf(a.w, c.w);
            } else {
                v[0] = a.x; v[1] = a.y; v[2] = a.z; v[3] = a.w;
            }
        } else {
            // H half: max(s_i, s_{i+2048}) for i<1024, FLT_MAX above
            if (lbase < 1024) {
                float4 a = xr4[tid];
                float4 c = xr4[tid + 512];
                v[0] = fmaxf(a.x, c.x); v[1] = fmaxf(a.y, c.y);
                v[2] = fmaxf(a.z, c.z); v[3] = fmaxf(a.w, c.w);
            } else {
                v[0] = v[1] = v[2] = v[3] = FLT_MAX;
            }
        }

        ((float4*)smem)[tid] = make_float4(v[0], v[1], v[2], v[3]);
        __syncthreads();
        for (int j = 1024; j >= 256; j >>= 1) {
            #pragma unroll
            for (int u = 0; u < 2; u++) {
                int p = tid + u * 512;
                int i = ((p & ~(j - 1)) << 1) | (p & (j - 1));
                int pj = i | j;
                float a = smem[i], b2 = smem[pj];
                if (a > b2) { smem[i] = b2; smem[pj] = a; }   // ascending
            }
            __syncthreads();
        }
        {
            float4 t4 = ((float4*)smem)[tid];
            v[0] = t4.x; v[1] = t4.y; v[2] = t4.z; v[3] = t4.w;
        }
        for (int j = 128; j >= 4; j >>= 1) {
            int lx = j >> 2;
            bool sel = ((tid & lx) == 0);
            #pragma unroll
            for (int r = 0; r < 4; r++) {
                float p = __shfl_xor(v[r], lx, 64);
                v[r] = sel ? fminf(v[r], p) : fmaxf(v[r], p);
            }
        }
        cas(v[0], v[2], true);
        cas(v[1], v[3], true);
        cas(v[0], v[1], true);
        cas(v[2], v[3], true);

        int gbase = half * NP1 + lbase;
        if (gbase < N) {
            float* dst = xs2 + (size_t)row * N + gbase;
            st_agent_f2(dst, v[0], v[1]);
            st_agent_f2(dst + 2, v[2], v[3]);
        }
    }

    // ---------------- flag merge done (no wait here) ----------------------
    asm volatile("s_waitcnt vmcnt(0)" ::: "memory");
    __syncthreads();
    if (tid == 0) {
        __hip_atomic_fetch_add(&g_merge[bid], 1u, __ATOMIC_RELAXED,
                               __HIP_MEMORY_SCOPE_AGENT);
    }

    // ---------------- phase 3: pair tiles (validated math) ----------------
    {
        // maxv from locally computed diag (bit-identical to zcos diagonal)
        if (tid < 64) {
            float vv = fmaxf(diag[tid], diag[tid + 64]);
            #pragma unroll
            for (int o = 32; o > 0; o >>= 1) vv = fmaxf(vv, __shfl_down(vv, o, 64));
            if (tid == 0) s_maxv = vv;
        }
        __syncthreads();
        float maxv = s_maxv;

        int w = tid >> 6;                  // wave 0..7
        int lane = tid & 63;
        float acc = 0.f;

        // 2048 primary tiles (one per wave) + 32 leftovers spread across 32
        // DIFFERENT blocks (wave 0 of every 8th block) for balance.
        int nT = (w == 0 && (bid & 7) == 0) ? 2 : 1;
        for (int pass = 0; pass < nT; ++pass) {
            int T = (pass == 0) ? (bid * 8 + w) : (2048 + (bid >> 3));

            // decode T -> (ti, tj), ti<=tj over TROW=64 (validated decode)
            float ff = (float)(2 * TROW + 1);
            int ti = (int)((ff - sqrtf(ff * ff - 8.0f * (float)T)) * 0.5f);
            if (ti < 0) ti = 0;
            if (ti > TROW - 1) ti = TROW - 1;
            while ((ti + 1) * TROW - ((ti + 1) * ti) / 2 <= T) ti++;
            while (ti * TROW - (ti * (ti - 1)) / 2 > T) ti--;
            int tj = ti + (T - (ti * TROW - (ti * (ti - 1)) / 2));

            int r0 = 2 * ti, r1 = r0 + 1;
            int c0 = 2 * tj, c1 = c0 + 1;

            // per-tile wait: merged rows r0,r1 <- blocks 4ti..4ti+3;
            //                merged rows c0,c1 <- blocks 4tj..4tj+3.
            // (also covers these rows' zcos entries: zcos row written by the
            //  same block pair, before their merge flags.)
            if (lane == 0) {
                #pragma unroll
                for (int q = 0; q < 4; q++) {
                    while (ld_flag(&g_merge[4 * ti + q]) < gen)
                        __builtin_amdgcn_s_sleep(1);
                    while (ld_flag(&g_merge[4 * tj + q]) < gen)
                        __builtin_amdgcn_s_sleep(1);
                }
            }

            const float4* a0 = (const float4*)(xs2 + (size_t)r0 * N);
            const float4* a1 = (const float4*)(xs2 + (size_t)r1 * N);
            const float4* b0 = (const float4*)(xs2 + (size_t)c0 * N);
            const float4* b1 = (const float4*)(xs2 + (size_t)c1 * N);

            float s00 = 0.f, s01 = 0.f, s10 = 0.f, s11 = 0.f;
            #pragma unroll
            for (int u = 0; u < N / 4 / 64; u++) {          // 12 iterations
                int idx = lane + u * 64;
                float4 va0 = a0[idx], va1 = a1[idx];
                float4 vb0 = b0[idx], vb1 = b1[idx];
                s00 += fabsf(va0.x - vb0.x) + fabsf(va0.y - vb0.y)
                     + fabsf(va0.z - vb0.z) + fabsf(va0.w - vb0.w);
                s01 += fabsf(va0.x - vb1.x) + fabsf(va0.y - vb1.y)
                     + fabsf(va0.z - vb1.z) + fabsf(va0.w - vb1.w);
                s10 += fabsf(va1.x - vb0.x) + fabsf(va1.y - vb0.y)
                     + fabsf(va1.z - vb0.z) + fabsf(va1.w - vb0.w);
                s11 += fabsf(va1.x - vb1.x) + fabsf(va1.y - vb1.y)
                     + fabsf(va1.z - vb1.z) + fabsf(va1.w - vb1.w);
            }
            #pragma unroll
            for (int o = 32; o > 0; o >>= 1) {
                s00 += __shfl_down(s00, o, 64);
                s01 += __shfl_down(s01, o, 64);
                s10 += __shfl_down(s10, o, 64);
                s11 += __shfl_down(s11, o, 64);
            }
            if (lane == 0) {
                bool diagt = (ti == tj);
                float w00 = diagt ? 1.0f : 2.0f;
                float w01 = 2.0f;
                float w10 = diagt ? 0.0f : 2.0f;
                float w11 = diagt ? 1.0f : 2.0f;
                float inv_n = 1.0f / N;
                float d00 = s00 * inv_n - (maxv - zcos[r0 * B + c0]);
                float d01 = s01 * inv_n - (maxv - zcos[r0 * B + c1]);
                float d10 = s10 * inv_n - (maxv - zcos[r1 * B + c0]);
                float d11 = s11 * inv_n - (maxv - zcos[r1 * B + c1]);
                acc += w00 * d00 * d00 + w01 * d01 * d01
                     + w10 * d10 * d10 + w11 * d11 * d11;
            }
        }
        if (lane == 0) partial[w] = acc;
        __syncthreads();
        if (tid == 0) {
            while (ld_flag(&g_outz) < gen) __builtin_amdgcn_s_sleep(1);
            float blk = partial[0] + partial[1] + partial[2] + partial[3]
                      + partial[4] + partial[5] + partial[6] + partial[7];
            atomicAdd(out, blk * (1.0f / (B * B)));
        }
    }
}

extern "C" void kernel_launch(void* const* d_in, const int* in_sizes, int n_in,
                              void* d_out, int out_size, void* d_ws, size_t ws_size,
                              hipStream_t stream) {
    const float* z = (const float*)d_in[0];   // [128,128]
    const float* x = (const float*)d_in[1];   // [128,3,32,32]
    float* out = (float*)d_out;               // [1]
    float* ws = (float*)d_ws;

    float* zcos = ws;                         // 16384 floats
    float* xs   = ws + 16384;                 // 393216 floats (sorted halves)
    float* xs2  = ws + 16384 + 393216;        // 393216 floats (merged rows)

    fused_kernel<<<GRID, NTHREADS, 0, stream>>>(x, z, xs, xs2, zcos, out);
}